// Round 6
// baseline (217.964 us; speedup 1.0000x reference)
//
#include <hip/hip_runtime.h>
#include <hip/hip_fp16.h>

// InnerProductDecoder2: fused edge gather + gumbel-argmax + sigmoid select.
// Round-6: 8-lane groups x dwordx4 gathers (16 VMEM/batch, same lines),
// v_dot2_f32_f16 packed dots (4x less dot VALU), 3-step reduce, and the
// borderline-f64 path deferred to a fixup kernel over a compacted list.
// Borderline margin |vf+g0-g1| < TAU=0.05 (~9 sigma of fp16 dot error,
// expected max-over-3.2M error ~0.03) recomputed exactly in f64 mirroring
// the float64 numpy reference -> discrete flag never flips.

constexpr int D = 64;
#define TAU 0.05f

using half2v = _Float16 __attribute__((ext_vector_type(2)));

static __device__ __forceinline__ float2 h2f2(unsigned int u)
{
    return __half22float2(__builtin_bit_cast(__half2, u));
}

static __device__ __forceinline__ float fdot2f(unsigned int a, unsigned int b, float c)
{
#if __has_builtin(__builtin_amdgcn_fdot2)
    return __builtin_amdgcn_fdot2(__builtin_bit_cast(half2v, a),
                                  __builtin_bit_cast(half2v, b), c, false);
#else
    const float2 fa = h2f2(a), fb = h2f2(b);
    return c + fa.x * fb.x + fa.y * fb.y;
#endif
}

// Detect whether edge_index was passed as int64 or int32.
__global__ void detect_i64_kernel(const void* __restrict__ eidx, long long nmax,
                                  int nsamp, int* __restrict__ flag)
{
    if (blockIdx.x == 0 && threadIdx.x == 0) {
        const long long* p = (const long long*)eidx;
        int ok = 1;
        for (int i = 0; i < nsamp; ++i) {
            long long v = p[i];
            if (v < 0 || v >= nmax) { ok = 0; break; }
        }
        *flag = ok;
    }
}

// f32 -> f16 conversion of z1 (4 elems per thread, fully coalesced)
__global__ __launch_bounds__(256) void cvt_half_kernel(
    const float* __restrict__ z1, __half* __restrict__ zh, long long n4)
{
    long long i = (long long)blockIdx.x * blockDim.x + threadIdx.x;
    const long long stride = (long long)gridDim.x * blockDim.x;
    for (; i < n4; i += stride) {
        const float4 v = *(const float4*)(z1 + i * 4);
        __half2 h0 = __floats2half2_rn(v.x, v.y);
        __half2 h1 = __floats2half2_rn(v.z, v.w);
        uint2 o;
        o.x = __builtin_bit_cast(unsigned int, h0);
        o.y = __builtin_bit_cast(unsigned int, h1);
        *(uint2*)(zh + i * 4) = o;
    }
}

// exact f64 recompute of one edge, mirroring the float64 numpy reference
static __device__ __forceinline__ void exact_edge(
    const float* __restrict__ z1, const float* __restrict__ gu,
    bool is64, bool tpos, const void* __restrict__ eidx, int E, long long e,
    float* sg_out, float* flag_out)
{
    long long s, d;
    if (is64) { s = ((const long long*)eidx)[e]; d = ((const long long*)eidx)[E + e]; }
    else      { s = ((const int*)eidx)[e];       d = ((const int*)eidx)[E + e]; }
    const float* ra = z1 + s * D;
    const float* rb = z1 + d * D;
    double acc = 0.0;
    for (int j = 2; j < D; ++j)
        acc += (double)ra[j] * (double)rb[j];
    const float2 uu = *(const float2*)(gu + 2 * e);
    const double w0 = fmin(fmax((double)uu.x, 1e-10), 1.0 - 1e-10);
    const double w1 = fmin(fmax((double)uu.y, 1e-10), 1.0 - 1e-10);
    const double G0 = -log(-log(w0));
    const double G1 = -log(-log(w1));
    const double N0 = acc + G0;
    const bool f2 = tpos ? (N0 >= G1) : (N0 <= G1);
    const double xx = f2 ? acc : ((double)ra[0] + (double)rb[0]);
    *sg_out   = (float)(1.0 / (1.0 + exp(-xx)));
    *flag_out = f2 ? 1.0f : 0.0f;
}

// fixup kernel: exact f64 over the compacted borderline list
__global__ __launch_bounds__(256) void fixup_kernel(
    const float* __restrict__ z1, const float* __restrict__ gu,
    const int* __restrict__ temp_p, const void* __restrict__ eidx,
    float* __restrict__ out, int E, const int* __restrict__ i64flag,
    const int* __restrict__ ctr, const int* __restrict__ list)
{
    const bool is64 = (*i64flag != 0);
    const bool tpos = (*temp_p > 0);
    const int n = *ctr;
    for (int i = blockIdx.x * blockDim.x + threadIdx.x; i < n;
         i += gridDim.x * blockDim.x) {
        const long long e = list[i];
        float sg, fl;
        exact_edge(z1, gu, is64, tpos, eidx, E, e, &sg, &fl);
        out[e]     = sg;
        out[E + e] = fl;
    }
}

// ---------------- fp16-gather main kernel ----------------
// DEFER=true: borderline edges appended to list (fixup kernel resolves).
// DEFER=false: inline f64 resolve (used when ws too small for the list).
template <bool DEFER>
__global__ __launch_bounds__(256, 4) void ipd2_h8_kernel(
    const float* __restrict__ z1,
    const __half* __restrict__ zh,
    const float* __restrict__ gu,
    const int* __restrict__ temp_p,
    const void* __restrict__ eidx,
    float* __restrict__ out,
    int E,
    const int* __restrict__ i64flag,
    int* __restrict__ ctr,
    int* __restrict__ list)
{
    const bool is64 = (*i64flag != 0);
    const bool tpos = (*temp_p > 0);

    __shared__ float s_vf[4][64];
    __shared__ float s_vn[4][64];

    const int lane = threadIdx.x & 63;
    const int wid  = threadIdx.x >> 6;
    const int grp  = lane >> 3;              // 8-lane group (0..7)
    const int sub  = lane & 7;

    const long long wgid   = ((long long)blockIdx.x * blockDim.x + threadIdx.x) >> 6;
    const long long nwaves = ((long long)gridDim.x * blockDim.x) >> 6;
    const long long bstep  = nwaves * 64;

    const int*       p32 = (const int*)eidx;
    const long long* p64 = (const long long*)eidx;

    const long long base0 = wgid * 64;
    if (base0 >= E) return;

    // prologue: batch-0 indices + gumbel (clamped)
    long long e0 = base0 + lane; if (e0 >= E) e0 = E - 1;
    int sj, dj;
    if (is64) { sj = (int)p64[e0]; dj = (int)p64[E + e0]; }
    else      { sj = p32[e0];      dj = p32[E + e0]; }
    float2 uu = *(const float2*)(gu + 2 * e0);

    for (long long base = base0; base < E; base += bstep) {
        const long long eL  = base + lane;
        const bool      okL = eL < E;

        // prefetch NEXT batch's indices + gumbel (branchless, clamped)
        long long eN = base + bstep + lane;
        if (eN >= E) eN = E - 1;
        int nsj, ndj;
        if (is64) { nsj = (int)p64[eN]; ndj = (int)p64[E + eN]; }
        else      { nsj = p32[eN];      ndj = p32[E + eN]; }
        const float2 nuu = *(const float2*)(gu + 2 * eN);

        // tail VALU hoisted over gather latency
        const float u0 = fminf(fmaxf(uu.x, 1e-10f), 0.99999994f);
        const float u1 = fminf(fmaxf(uu.y, 1e-10f), 0.99999994f);
        const float g0 = -logf(-logf(u0));
        const float g1 = -logf(-logf(u1));

        // ---- phase 1: dots; group g -> edges base+g*8+k; lane covers halfs [8sub,8sub+8)
        if (base + 64 <= E) {
            uint4 a[8], b[8];
            #pragma unroll
            for (int k = 0; k < 8; ++k) {
                const int sl = grp * 8 + k;          // lane holding this edge's idx
                const int s  = __shfl(sj, sl, 64);
                const int d  = __shfl(dj, sl, 64);
                a[k] = *(const uint4*)(zh + (size_t)s * D + sub * 8);
                b[k] = *(const uint4*)(zh + (size_t)d * D + sub * 8);
            }
            #pragma unroll
            for (int k = 0; k < 8; ++k) {
                float acc = fdot2f(a[k].x, b[k].x, 0.0f);
                acc = fdot2f(a[k].y, b[k].y, acc);
                acc = fdot2f(a[k].z, b[k].z, acc);
                acc = fdot2f(a[k].w, b[k].w, acc);
                #pragma unroll
                for (int m = 1; m < 8; m <<= 1)
                    acc += __shfl_xor(acc, m, 64);   // stays within 8-lane group
                if (sub == 0) {
                    // remove cols 0,1 (z1[:,2:]) and record vn = a0 + b0
                    const float2 fa0 = h2f2(a[k].x), fb0 = h2f2(b[k].x);
                    acc -= fa0.x * fb0.x + fa0.y * fb0.y;
                    s_vf[wid][grp * 8 + k] = acc;
                    s_vn[wid][grp * 8 + k] = fa0.x + fb0.x;
                }
            }
        } else {
            // generic tail batch (only when 64 does not divide E)
            for (int it = 0; it < 8; ++it) {
                const long long e = base + grp * 8 + it;
                const int s = __shfl(sj, grp * 8 + it, 64);
                const int d = __shfl(dj, grp * 8 + it, 64);
                if (e < E) {
                    const uint4 a = *(const uint4*)(zh + (size_t)s * D + sub * 8);
                    const uint4 b = *(const uint4*)(zh + (size_t)d * D + sub * 8);
                    float acc = fdot2f(a.x, b.x, 0.0f);
                    acc = fdot2f(a.y, b.y, acc);
                    acc = fdot2f(a.z, b.z, acc);
                    acc = fdot2f(a.w, b.w, acc);
                    #pragma unroll
                    for (int m = 1; m < 8; m <<= 1)
                        acc += __shfl_xor(acc, m, 64);
                    if (sub == 0) {
                        const float2 fa0 = h2f2(a.x), fb0 = h2f2(b.x);
                        acc -= fa0.x * fb0.x + fa0.y * fb0.y;
                        s_vf[wid][grp * 8 + it] = acc;
                        s_vn[wid][grp * 8 + it] = fa0.x + fb0.x;
                    }
                }
            }
        }

        // ---- phase 2: tails, lane j -> edge base+j ----
        if (okL) {
            const float vf = s_vf[wid][lane];
            const float vn = s_vn[wid][lane];

            const float n0 = vf + g0;
            // argmax(softmax((la+g)/t)) monotone in la+g for t>0, reversed t<0;
            // tie -> index 0 -> flag = 1.
            bool  flag  = tpos ? (n0 >= g1) : (n0 <= g1);
            float x     = flag ? vf : vn;
            float sg    = 1.0f / (1.0f + expf(-x));
            float oflag = flag ? 1.0f : 0.0f;

            const bool border = fabsf(n0 - g1) < TAU;
            if (DEFER) {
                if (border) {
                    const int slot = atomicAdd(ctr, 1);
                    list[slot] = (int)eL;
                }
            } else if (border) {
                exact_edge(z1, gu, is64, tpos, eidx, E, eL, &sg, &oflag);
            }

            out[eL]     = sg;
            out[E + eL] = oflag;
        }

        sj = nsj; dj = ndj; uu = nuu;
    }
}

extern "C" void kernel_launch(void* const* d_in, const int* in_sizes, int n_in,
                              void* d_out, int out_size, void* d_ws, size_t ws_size,
                              hipStream_t stream)
{
    const float* z1     = (const float*)d_in[0];
    const float* gu     = (const float*)d_in[1];
    const int*   temp_p = (const int*)d_in[2];
    const void*  eidx   = d_in[3];
    float*       out    = (float*)d_out;

    const int E = in_sizes[1] / 2;          // gumbel_u is (E,2)
    const long long N = in_sizes[0] / D;    // z1 is (N,64)

    // ws layout: [0]=i64 flag, [1]=borderline counter, 4096: zh, then list
    int* i64flag = (int*)d_ws;
    int* ctr     = i64flag + 1;
    const size_t zh_bytes   = (size_t)N * D * sizeof(__half);
    const size_t need_basic = 4096 + zh_bytes;
    const size_t need_defer = need_basic + (size_t)E * sizeof(int);

    detect_i64_kernel<<<1, 64, 0, stream>>>(eidx, N, 128, i64flag);

    if (ws_size >= need_basic) {
        __half* zh = (__half*)((char*)d_ws + 4096);
        cvt_half_kernel<<<2048, 256, 0, stream>>>(z1, zh, (long long)N * D / 4);
        if (ws_size >= need_defer) {
            int* list = (int*)((char*)d_ws + 4096 + zh_bytes);
            hipMemsetAsync(ctr, 0, sizeof(int), stream);
            ipd2_h8_kernel<true><<<4096, 256, 0, stream>>>(
                z1, zh, gu, temp_p, eidx, out, E, i64flag, ctr, list);
            fixup_kernel<<<256, 256, 0, stream>>>(
                z1, gu, temp_p, eidx, out, E, i64flag, ctr, list);
        } else {
            ipd2_h8_kernel<false><<<4096, 256, 0, stream>>>(
                z1, zh, gu, temp_p, eidx, out, E, i64flag, ctr, nullptr);
        }
    } else {
        // no room for zh: run the f16-free inline variant on the f32 data is
        // not available here; fall back to a minimal-correct path using the
        // deferless kernel on a zh aliased to... not possible -> use inline
        // f64-free f32 path via the same kernel structure is omitted; in
        // practice ws_size >= 26 MB (validated in rounds 5/6).
        ipd2_h8_kernel<false><<<4096, 256, 0, stream>>>(
            z1, (const __half*)d_ws, gu, temp_p, eidx, out, E, i64flag, ctr, nullptr);
    }
}

// Round 7
// 144.513 us; speedup vs baseline: 1.5083x; 1.5083x over previous
//
#include <hip/hip_runtime.h>
#include <hip/hip_fp16.h>

// InnerProductDecoder2: fused edge gather + gumbel-argmax + sigmoid select.
// Round-7: round-6's VALU savings (8-lane groups, dwordx4 gathers, fdot2)
// with round-5's register budget: stage only 4 edges/group at a time
// (uint4 a[4],b[4] = 32 VGPRs) so total stays ~62 and nothing spills.
// Round-6's 4x WRITE_SIZE (99.8 MB vs 25 MB output) + extra fetch was
// scratch spill from 64 VGPRs of staging. Borderline argmax edges
// (|vf+g0-g1| < TAU) resolved inline in f64 mirroring the float64 numpy
// reference (proven structure from round 5).

constexpr int D = 64;
#define TAU 0.05f

using half2v = _Float16 __attribute__((ext_vector_type(2)));

static __device__ __forceinline__ float2 h2f2(unsigned int u)
{
    return __half22float2(__builtin_bit_cast(__half2, u));
}

static __device__ __forceinline__ float fdot2f(unsigned int a, unsigned int b, float c)
{
#if __has_builtin(__builtin_amdgcn_fdot2)
    return __builtin_amdgcn_fdot2(__builtin_bit_cast(half2v, a),
                                  __builtin_bit_cast(half2v, b), c, false);
#else
    const float2 fa = h2f2(a), fb = h2f2(b);
    return c + fa.x * fb.x + fa.y * fb.y;
#endif
}

// Detect whether edge_index was passed as int64 or int32.
__global__ void detect_i64_kernel(const void* __restrict__ eidx, long long nmax,
                                  int nsamp, int* __restrict__ flag)
{
    if (blockIdx.x == 0 && threadIdx.x == 0) {
        const long long* p = (const long long*)eidx;
        int ok = 1;
        for (int i = 0; i < nsamp; ++i) {
            long long v = p[i];
            if (v < 0 || v >= nmax) { ok = 0; break; }
        }
        *flag = ok;
    }
}

// f32 -> f16 conversion of z1 (4 elems per thread, fully coalesced)
__global__ __launch_bounds__(256) void cvt_half_kernel(
    const float* __restrict__ z1, __half* __restrict__ zh, long long n4)
{
    long long i = (long long)blockIdx.x * blockDim.x + threadIdx.x;
    const long long stride = (long long)gridDim.x * blockDim.x;
    for (; i < n4; i += stride) {
        const float4 v = *(const float4*)(z1 + i * 4);
        __half2 h0 = __floats2half2_rn(v.x, v.y);
        __half2 h1 = __floats2half2_rn(v.z, v.w);
        uint2 o;
        o.x = __builtin_bit_cast(unsigned int, h0);
        o.y = __builtin_bit_cast(unsigned int, h1);
        *(uint2*)(zh + i * 4) = o;
    }
}

// exact f64 recompute of one edge, mirroring the float64 numpy reference
static __device__ __forceinline__ void exact_edge(
    const float* __restrict__ z1, const float* __restrict__ gu,
    bool is64, bool tpos, const void* __restrict__ eidx, int E, long long e,
    float* sg_out, float* flag_out)
{
    long long s, d;
    if (is64) { s = ((const long long*)eidx)[e]; d = ((const long long*)eidx)[E + e]; }
    else      { s = ((const int*)eidx)[e];       d = ((const int*)eidx)[E + e]; }
    const float* ra = z1 + s * D;
    const float* rb = z1 + d * D;
    double acc = 0.0;
    for (int j = 2; j < D; ++j)
        acc += (double)ra[j] * (double)rb[j];
    const float2 uu = *(const float2*)(gu + 2 * e);
    const double w0 = fmin(fmax((double)uu.x, 1e-10), 1.0 - 1e-10);
    const double w1 = fmin(fmax((double)uu.y, 1e-10), 1.0 - 1e-10);
    const double G0 = -log(-log(w0));
    const double G1 = -log(-log(w1));
    const double N0 = acc + G0;
    const bool f2 = tpos ? (N0 >= G1) : (N0 <= G1);
    const double xx = f2 ? acc : ((double)ra[0] + (double)rb[0]);
    *sg_out   = (float)(1.0 / (1.0 + exp(-xx)));
    *flag_out = f2 ? 1.0f : 0.0f;
}

// ---------------- fp16-gather main kernel ----------------
__global__ __launch_bounds__(256, 4) void ipd2_h8_kernel(
    const float* __restrict__ z1,        // original f32 (borderline fallback)
    const __half* __restrict__ zh,       // fp16 copy (fast path)
    const float* __restrict__ gu,
    const int* __restrict__ temp_p,
    const void* __restrict__ eidx,
    float* __restrict__ out,
    int E,
    const int* __restrict__ i64flag)
{
    const bool is64 = (*i64flag != 0);
    const bool tpos = (*temp_p > 0);

    __shared__ float s_vf[4][64];
    __shared__ float s_vn[4][64];

    const int lane = threadIdx.x & 63;
    const int wid  = threadIdx.x >> 6;
    const int grp  = lane >> 3;              // 8-lane group (0..7)
    const int sub  = lane & 7;

    const long long wgid   = ((long long)blockIdx.x * blockDim.x + threadIdx.x) >> 6;
    const long long nwaves = ((long long)gridDim.x * blockDim.x) >> 6;
    const long long bstep  = nwaves * 64;

    const int*       p32 = (const int*)eidx;
    const long long* p64 = (const long long*)eidx;

    const long long base0 = wgid * 64;
    if (base0 >= E) return;

    // prologue: batch-0 indices + gumbel (clamped)
    long long e0 = base0 + lane; if (e0 >= E) e0 = E - 1;
    int sj, dj;
    if (is64) { sj = (int)p64[e0]; dj = (int)p64[E + e0]; }
    else      { sj = p32[e0];      dj = p32[E + e0]; }
    float2 uu = *(const float2*)(gu + 2 * e0);

    for (long long base = base0; base < E; base += bstep) {
        const long long eL  = base + lane;
        const bool      okL = eL < E;

        // prefetch NEXT batch's indices + gumbel (branchless, clamped)
        long long eN = base + bstep + lane;
        if (eN >= E) eN = E - 1;
        int nsj, ndj;
        if (is64) { nsj = (int)p64[eN]; ndj = (int)p64[E + eN]; }
        else      { nsj = p32[eN];      ndj = p32[E + eN]; }
        const float2 nuu = *(const float2*)(gu + 2 * eN);

        // tail VALU hoisted over gather latency
        const float u0 = fminf(fmaxf(uu.x, 1e-10f), 0.99999994f);
        const float u1 = fminf(fmaxf(uu.y, 1e-10f), 0.99999994f);
        const float g0 = -logf(-logf(u0));
        const float g1 = -logf(-logf(u1));

        // ---- phase 1: dots; group g owns edges base+g*8..base+g*8+7.
        // Staged in two half-batches of 4 edges/group: uint4 a[4],b[4] = 32
        // VGPRs live (NOT 64 -> no spill, round-6 lesson).
        if (base + 64 <= E) {
            #pragma unroll
            for (int half = 0; half < 2; ++half) {
                uint4 a[4], b[4];
                #pragma unroll
                for (int k = 0; k < 4; ++k) {
                    const int sl = grp * 8 + half * 4 + k;  // owner lane
                    const int s  = __shfl(sj, sl, 64);
                    const int d  = __shfl(dj, sl, 64);
                    a[k] = *(const uint4*)(zh + (size_t)s * D + sub * 8);
                    b[k] = *(const uint4*)(zh + (size_t)d * D + sub * 8);
                }
                #pragma unroll
                for (int k = 0; k < 4; ++k) {
                    // lane covers halfs [8*sub, 8*sub+8); a.x = cols {8s,8s+1}
                    const float t0 = fdot2f(a[k].x, b[k].x, 0.0f);
                    float acc = (sub == 0) ? 0.0f : t0;   // exclude cols 0,1
                    acc = fdot2f(a[k].y, b[k].y, acc);
                    acc = fdot2f(a[k].z, b[k].z, acc);
                    acc = fdot2f(a[k].w, b[k].w, acc);
                    #pragma unroll
                    for (int m = 1; m < 8; m <<= 1)
                        acc += __shfl_xor(acc, m, 64);    // within 8-lane group
                    if (sub == 0) {
                        s_vf[wid][grp * 8 + half * 4 + k] = acc;
                        s_vn[wid][grp * 8 + half * 4 + k] =
                            h2f2(a[k].x).x + h2f2(b[k].x).x;   // col0 + col0
                    }
                }
            }
        } else {
            // generic tail batch (only when 64 does not divide E)
            for (int it = 0; it < 8; ++it) {
                const long long e = base + grp * 8 + it;
                const int s = __shfl(sj, grp * 8 + it, 64);
                const int d = __shfl(dj, grp * 8 + it, 64);
                if (e < E) {
                    const uint4 a = *(const uint4*)(zh + (size_t)s * D + sub * 8);
                    const uint4 b = *(const uint4*)(zh + (size_t)d * D + sub * 8);
                    const float t0 = fdot2f(a.x, b.x, 0.0f);
                    float acc = (sub == 0) ? 0.0f : t0;
                    acc = fdot2f(a.y, b.y, acc);
                    acc = fdot2f(a.z, b.z, acc);
                    acc = fdot2f(a.w, b.w, acc);
                    #pragma unroll
                    for (int m = 1; m < 8; m <<= 1)
                        acc += __shfl_xor(acc, m, 64);
                    if (sub == 0) {
                        s_vf[wid][grp * 8 + it] = acc;
                        s_vn[wid][grp * 8 + it] = h2f2(a.x).x + h2f2(b.x).x;
                    }
                }
            }
        }

        // ---- phase 2: tails, lane j -> edge base+j ----
        if (okL) {
            const float vf = s_vf[wid][lane];
            const float vn = s_vn[wid][lane];

            const float n0 = vf + g0;
            // argmax(softmax((la+g)/t)) monotone in la+g for t>0, reversed t<0;
            // tie -> index 0 -> flag = 1.
            bool  flag  = tpos ? (n0 >= g1) : (n0 <= g1);
            float x     = flag ? vf : vn;
            float sg    = 1.0f / (1.0f + expf(-x));
            float oflag = flag ? 1.0f : 0.0f;

            if (fabsf(n0 - g1) < TAU) {
                exact_edge(z1, gu, is64, tpos, eidx, E, eL, &sg, &oflag);
            }

            out[eL]     = sg;
            out[E + eL] = oflag;
        }

        sj = nsj; dj = ndj; uu = nuu;
    }
}

// ---------------- f32 fallback (round-4 proven kernel) for small ws ----------------
__global__ __launch_bounds__(256, 4) void ipd2_f32_kernel(
    const float* __restrict__ z1,
    const float* __restrict__ gu,
    const int* __restrict__ temp_p,
    const void* __restrict__ eidx,
    float* __restrict__ out,
    int E,
    const int* __restrict__ i64flag)
{
    const bool is64 = (*i64flag != 0);
    const bool tpos = (*temp_p > 0);

    __shared__ float s_vf[4][64];
    __shared__ float s_vn[4][64];

    const int lane = threadIdx.x & 63;
    const int wid  = threadIdx.x >> 6;
    const int grp  = lane >> 4;
    const int sub  = lane & 15;

    const long long wgid   = ((long long)blockIdx.x * blockDim.x + threadIdx.x) >> 6;
    const long long nwaves = ((long long)gridDim.x * blockDim.x) >> 6;
    const long long bstep  = nwaves * 64;

    const int*       p32 = (const int*)eidx;
    const long long* p64 = (const long long*)eidx;

    const long long base0 = wgid * 64;
    if (base0 >= E) return;

    long long e0 = base0 + lane; if (e0 >= E) e0 = E - 1;
    int sj, dj;
    if (is64) { sj = (int)p64[e0]; dj = (int)p64[E + e0]; }
    else      { sj = p32[e0];      dj = p32[E + e0]; }
    float2 uu = *(const float2*)(gu + 2 * e0);

    for (long long base = base0; base < E; base += bstep) {
        const long long eL  = base + lane;
        const bool      okL = eL < E;

        long long eN = base + bstep + lane;
        if (eN >= E) eN = E - 1;
        int nsj, ndj;
        if (is64) { nsj = (int)p64[eN]; ndj = (int)p64[E + eN]; }
        else      { nsj = p32[eN];      ndj = p32[E + eN]; }
        const float2 nuu = *(const float2*)(gu + 2 * eN);

        const float u0 = fminf(fmaxf(uu.x, 1e-10f), 0.99999994f);
        const float u1 = fminf(fmaxf(uu.y, 1e-10f), 0.99999994f);
        const float g0 = -logf(-logf(u0));
        const float g1 = -logf(-logf(u1));

        for (int it0 = 0; it0 < 16; it0 += 4) {
            float4 a[4], b[4];
            #pragma unroll
            for (int k = 0; k < 4; ++k) {
                const int sl = grp * 16 + it0 + k;
                const int s  = __shfl(sj, sl, 64);
                const int d  = __shfl(dj, sl, 64);
                long long e = base + sl;
                const size_t so = (e < E) ? (size_t)s * D : 0;
                const size_t dofs = (e < E) ? (size_t)d * D : 0;
                a[k] = *(const float4*)(z1 + so + sub * 4);
                b[k] = *(const float4*)(z1 + dofs + sub * 4);
            }
            #pragma unroll
            for (int k = 0; k < 4; ++k) {
                float loc = a[k].z * b[k].z + a[k].w * b[k].w;
                if (sub != 0) loc += a[k].x * b[k].x + a[k].y * b[k].y;
                #pragma unroll
                for (int m = 1; m < 16; m <<= 1)
                    loc += __shfl_xor(loc, m, 64);
                if (sub == 0) {
                    s_vf[wid][grp * 16 + it0 + k] = loc;
                    s_vn[wid][grp * 16 + it0 + k] = a[k].x + b[k].x;
                }
            }
        }

        if (okL) {
            const float vf = s_vf[wid][lane];
            const float vn = s_vn[wid][lane];
            const float n0 = vf + g0;
            bool  flag  = tpos ? (n0 >= g1) : (n0 <= g1);
            float x     = flag ? vf : vn;
            float sg    = 1.0f / (1.0f + expf(-x));
            float oflag = flag ? 1.0f : 0.0f;

            if (fabsf(n0 - g1) < 0.004f) {
                exact_edge(z1, gu, is64, tpos, eidx, E, eL, &sg, &oflag);
            }

            out[eL]     = sg;
            out[E + eL] = oflag;
        }

        sj = nsj; dj = ndj; uu = nuu;
    }
}

extern "C" void kernel_launch(void* const* d_in, const int* in_sizes, int n_in,
                              void* d_out, int out_size, void* d_ws, size_t ws_size,
                              hipStream_t stream)
{
    const float* z1     = (const float*)d_in[0];
    const float* gu     = (const float*)d_in[1];
    const int*   temp_p = (const int*)d_in[2];
    const void*  eidx   = d_in[3];
    float*       out    = (float*)d_out;

    const int E = in_sizes[1] / 2;          // gumbel_u is (E,2)
    const long long N = in_sizes[0] / D;    // z1 is (N,64)

    int* i64flag = (int*)d_ws;
    const size_t zh_bytes = (size_t)N * D * sizeof(__half);
    const size_t need     = 4096 + zh_bytes;

    detect_i64_kernel<<<1, 64, 0, stream>>>(eidx, N, 128, i64flag);

    if (ws_size >= need) {
        __half* zh = (__half*)((char*)d_ws + 4096);
        cvt_half_kernel<<<2048, 256, 0, stream>>>(z1, zh, (long long)N * D / 4);
        ipd2_h8_kernel<<<4096, 256, 0, stream>>>(
            z1, zh, gu, temp_p, eidx, out, E, i64flag);
    } else {
        ipd2_f32_kernel<<<4096, 256, 0, stream>>>(
            z1, gu, temp_p, eidx, out, E, i64flag);
    }
}